// Round 4
// baseline (221.524 us; speedup 1.0000x reference)
//
#include <hip/hip_runtime.h>
#include <cstddef>

// Sizes (fixed per reference): B=8192, D=784, H=256, E=32, K=512
#define NB 8192
#define ND 784
#define NH 256
#define NE 32
#define NK 512
#define ALPHA_F 1000.0f

typedef _Float16 h8 __attribute__((ext_vector_type(8)));
typedef _Float16 h4 __attribute__((ext_vector_type(4)));
typedef float f32x4 __attribute__((ext_vector_type(4)));

// ---------------------------------------------------------------------------
// Split fp32 -> (hi fp16, lo fp16 scaled by 2^11).  w ~= hi + lo * 2^-11,
// representation error ~2^-23|w|.  fp16*fp16 products are exact in the fp32
// MFMA accumulator, so a 3/4-term product expansion is fp32-class accurate.
// ---------------------------------------------------------------------------
__global__ __launch_bounds__(256)
void split_x_kernel(const float* __restrict__ x, _Float16* __restrict__ xhi,
                    _Float16* __restrict__ xlo, int n4) {
    int i = blockIdx.x * 256 + threadIdx.x;
    if (i >= n4) return;
    float4 v = ((const float4*)x)[i];
    float vv[4] = {v.x, v.y, v.z, v.w};
    h4 hi, lo;
    #pragma unroll
    for (int j = 0; j < 4; ++j) {
        _Float16 hh = (_Float16)vv[j];
        float r = vv[j] - (float)hh;
        hi[j] = hh;
        lo[j] = (_Float16)(r * 2048.0f);
    }
    ((h4*)xhi)[i] = hi;
    ((h4*)xlo)[i] = lo;
}

// W [K][N] fp32  ->  WT_hi/lo [N][K] fp16 (transposed, split). One block per n.
__global__ __launch_bounds__(256)
void splitw_kernel(const float* __restrict__ W, _Float16* __restrict__ hi,
                   _Float16* __restrict__ lo, int K, int N) {
    const int n = blockIdx.x;
    for (int k = threadIdx.x; k < K; k += 256) {
        float w = W[(size_t)k * N + n];
        _Float16 hh = (_Float16)w;
        float r = w - (float)hh;
        hi[(size_t)n * K + k] = hh;
        lo[(size_t)n * K + k] = (_Float16)(r * 2048.0f);
    }
}

// ---------------------------------------------------------------------------
// MFMA split-fp16 GEMM: C[M,N] = op(A[M,K] @ W[K,N] + bias)
// A given as hi/lo fp16 planes [M][K]; W given TRANSPOSED as hi/lo [N][K].
// Tile 64x64, BK=32, 256 threads = 4 waves, wave = 32x32 via 2x2 MFMA tiles
// of v_mfma_f32_16x16x32_f16.  TERMS=4: full hh+mid+ll (fp32-class, encoder);
// TERMS=3: drop ll (decoder).  K ragged: trailing 8-elem chunks zero-filled.
// LDS rows padded to 40 fp16 (80 B) to spread bank groups.
// ---------------------------------------------------------------------------
template<int TERMS, bool RELU>
__global__ __launch_bounds__(256)
void mfma_gemm(const _Float16* __restrict__ Ahi, const _Float16* __restrict__ Alo,
               const _Float16* __restrict__ WThi, const _Float16* __restrict__ WTlo,
               const float* __restrict__ bias, float* __restrict__ C,
               int N, int K, int KS) {
    __shared__ _Float16 smem[4 * 64 * 40];
    const int PA_HI = 0, PA_LO = 2560, PB_HI = 5120, PB_LO = 7680;

    const int tid = threadIdx.x;
    const int bm  = blockIdx.x * 64;
    const int bn  = blockIdx.y * 64;

    // staging: thread -> (row, 8-elem k-chunk)
    const int srow = tid >> 2;
    const int sq   = (tid & 3) * 8;
    const int arow_g = bm + srow;
    int brow_g = bn + srow; if (brow_g > N - 1) brow_g = N - 1;  // G4 edge tile

    const _Float16* pAhi = Ahi + (size_t)arow_g * K;
    const _Float16* pAlo = Alo + (size_t)arow_g * K;
    const _Float16* pBhi = WThi + (size_t)brow_g * K;
    const _Float16* pBlo = WTlo + (size_t)brow_g * K;

    auto ld8 = [&](const _Float16* p, int k) -> h8 {
        if (k + 8 <= K) return *(const h8*)(p + k);
        h8 z = {};
        return z;
    };

    h8 ra_hi = ld8(pAhi, sq), ra_lo = ld8(pAlo, sq);
    h8 rb_hi = ld8(pBhi, sq), rb_lo = ld8(pBlo, sq);

    // fragment coords
    const int lane = tid & 63;
    const int wv   = tid >> 6;
    const int mb   = (wv >> 1) * 32;
    const int nb   = (wv & 1) * 32;
    const int li   = lane & 15;
    const int kq   = (lane >> 4) * 8;

    f32x4 acc0[2][2] = {};
    f32x4 acc1[2][2] = {};
    f32x4 acc2[2][2] = {};

    const int soff = srow * 40 + sq;

    for (int s = 0; s < KS; ++s) {
        *(h8*)&smem[PA_HI + soff] = ra_hi;
        *(h8*)&smem[PA_LO + soff] = ra_lo;
        *(h8*)&smem[PB_HI + soff] = rb_hi;
        *(h8*)&smem[PB_LO + soff] = rb_lo;
        __syncthreads();

        if (s + 1 < KS) {
            const int kn = (s + 1) * 32 + sq;
            ra_hi = ld8(pAhi, kn); ra_lo = ld8(pAlo, kn);
            rb_hi = ld8(pBhi, kn); rb_lo = ld8(pBlo, kn);
        }

        h8 ahi[2], alo[2], bhi[2], blo[2];
        #pragma unroll
        for (int t = 0; t < 2; ++t) {
            const int ao = (mb + t * 16 + li) * 40 + kq;
            ahi[t] = *(const h8*)&smem[PA_HI + ao];
            alo[t] = *(const h8*)&smem[PA_LO + ao];
            const int bo = (nb + t * 16 + li) * 40 + kq;
            bhi[t] = *(const h8*)&smem[PB_HI + bo];
            blo[t] = *(const h8*)&smem[PB_LO + bo];
        }
        #pragma unroll
        for (int tm = 0; tm < 2; ++tm)
            #pragma unroll
            for (int tn = 0; tn < 2; ++tn) {
                acc0[tm][tn] = __builtin_amdgcn_mfma_f32_16x16x32_f16(
                    ahi[tm], bhi[tn], acc0[tm][tn], 0, 0, 0);
                acc1[tm][tn] = __builtin_amdgcn_mfma_f32_16x16x32_f16(
                    ahi[tm], blo[tn], acc1[tm][tn], 0, 0, 0);
                acc1[tm][tn] = __builtin_amdgcn_mfma_f32_16x16x32_f16(
                    alo[tm], bhi[tn], acc1[tm][tn], 0, 0, 0);
                if (TERMS == 4)
                    acc2[tm][tn] = __builtin_amdgcn_mfma_f32_16x16x32_f16(
                        alo[tm], blo[tn], acc2[tm][tn], 0, 0, 0);
            }
        __syncthreads();
    }

    const float c1 = 1.0f / 2048.0f;
    const float c2 = c1 * c1;
    const int quad = lane >> 4;
    #pragma unroll
    for (int tm = 0; tm < 2; ++tm)
        #pragma unroll
        for (int tn = 0; tn < 2; ++tn) {
            const int n = bn + nb + tn * 16 + li;
            if (n < N) {
                const float bv = bias[n];
                #pragma unroll
                for (int r = 0; r < 4; ++r) {
                    const int m = bm + mb + tm * 16 + quad * 4 + r;
                    float v = acc0[tm][tn][r] + c1 * acc1[tm][tn][r];
                    if (TERMS == 4) v += c2 * acc2[tm][tn][r];
                    v += bv;
                    if (RELU) v = fmaxf(v, 0.f);
                    C[(size_t)m * N + n] = v;
                }
            }
        }
}

// ---------------------------------------------------------------------------
// Fused: emb[B,32] = h@W2+b2 (fp32, precision-critical);
//        h2 = relu(emb@W3+b3) emitted as fp16 hi/lo planes for the MFMA GEMM.
// Block = 16 rows, 256 threads, 512 blocks.
// ---------------------------------------------------------------------------
__global__ __launch_bounds__(256)
void mid_kernel(const float* __restrict__ h, const float* __restrict__ W2,
                const float* __restrict__ b2, const float* __restrict__ W3,
                const float* __restrict__ b3, float* __restrict__ emb,
                _Float16* __restrict__ h2hi, _Float16* __restrict__ h2lo) {
    __shared__ float es[16][32];
    const int tid = threadIdx.x;
    const int r0  = blockIdx.x * 16;

    #pragma unroll
    for (int half = 0; half < 2; ++half) {
        const int o   = tid + half * 256;
        const int row = o >> 5;
        const int col = o & 31;
        const float* hrow = h + (size_t)(r0 + row) * NH;
        float acc0 = 0.f, acc1 = 0.f;
        #pragma unroll 4
        for (int k = 0; k < NH; k += 4) {
            float4 hv = *(const float4*)(hrow + k);
            acc0 = fmaf(hv.x, W2[(k + 0) * NE + col], acc0);
            acc1 = fmaf(hv.y, W2[(k + 1) * NE + col], acc1);
            acc0 = fmaf(hv.z, W2[(k + 2) * NE + col], acc0);
            acc1 = fmaf(hv.w, W2[(k + 3) * NE + col], acc1);
        }
        float v = acc0 + acc1 + b2[col];
        es[row][col] = v;
        emb[(size_t)r0 * NE + o] = v;
    }
    __syncthreads();

    const int col = tid;
    float acc[16];
    #pragma unroll
    for (int r = 0; r < 16; ++r) acc[r] = 0.f;
    #pragma unroll
    for (int k = 0; k < NE; ++k) {
        float w = W3[k * NH + col];
        #pragma unroll
        for (int r = 0; r < 16; ++r) acc[r] = fmaf(es[r][k], w, acc[r]);
    }
    const float bb = b3[col];
    #pragma unroll
    for (int r = 0; r < 16; ++r) {
        float v = acc[r] + bb;
        v = v > 0.f ? v : 0.f;
        _Float16 hh = (_Float16)v;
        float rr = v - (float)hh;
        h2hi[(size_t)(r0 + r) * NH + col] = hh;
        h2lo[(size_t)(r0 + r) * NH + col] = (_Float16)(rr * 2048.0f);
    }
}

// ---------------------------------------------------------------------------
// Distances + stable softmin, register-resident reps.
// 512 blocks x 256 threads, 16 rows/block. Thread owns clusters 2t, 2t+1
// (64 VGPRs of reps, loaded once from L2). emb tile in LDS (broadcast reads).
// No reps staging, no big LDS -> latency-light, VALU-dense.
// ---------------------------------------------------------------------------
__global__ __launch_bounds__(256)
void dist_kernel(const float* __restrict__ emb, const float* __restrict__ reps,
                 float* __restrict__ dist, float* __restrict__ wout) {
    __shared__ float es[16][32];
    __shared__ float smin[4][16];
    __shared__ float ssum[4][16];
    __shared__ float rmin[16];
    __shared__ float rinv[16];

    const int tid = threadIdx.x;
    const int r0  = blockIdx.x * 16;

    // reps for clusters 2t, 2t+1 -> registers (256 B contiguous per thread)
    const float* rp = reps + (size_t)tid * 64;
    f32x4 rv0[8], rv1[8];
    #pragma unroll
    for (int e4 = 0; e4 < 8; ++e4) {
        rv0[e4] = ((const f32x4*)rp)[e4];
        rv1[e4] = ((const f32x4*)rp)[e4 + 8];
    }

    // stage emb tile (16 rows x 32)
    es[tid >> 5][tid & 31] = emb[(size_t)r0 * NE + tid];
    es[(tid + 256) >> 5][tid & 31] = emb[(size_t)r0 * NE + tid + 256];
    __syncthreads();

    // distances
    float d0[16], d1[16];
    #pragma unroll
    for (int r = 0; r < 16; ++r) {
        float a0 = 0.f, a1 = 0.f;
        #pragma unroll
        for (int e4 = 0; e4 < 8; ++e4) {
            f32x4 ev = *(const f32x4*)&es[r][e4 * 4];
            #pragma unroll
            for (int j = 0; j < 4; ++j) {
                float t0 = ev[j] - rv0[e4][j]; a0 = fmaf(t0, t0, a0);
                float t1 = ev[j] - rv1[e4][j]; a1 = fmaf(t1, t1, a1);
            }
        }
        d0[r] = a0; d1[r] = a1;
    }

    const int lane = tid & 63;
    const int wid  = tid >> 6;

    // block-wide per-row min
    #pragma unroll
    for (int r = 0; r < 16; ++r) {
        float m = fminf(d0[r], d1[r]);
        #pragma unroll
        for (int off = 32; off > 0; off >>= 1)
            m = fminf(m, __shfl_xor(m, off, 64));
        if (lane == 0) smin[wid][r] = m;
    }
    __syncthreads();
    if (tid < 16)
        rmin[tid] = fminf(fminf(smin[0][tid], smin[1][tid]),
                          fminf(smin[2][tid], smin[3][tid]));
    __syncthreads();

    // block-wide per-row sum of exponentials
    #pragma unroll
    for (int r = 0; r < 16; ++r) {
        const float m = rmin[r];
        float s = expf(-ALPHA_F * (d0[r] - m)) + expf(-ALPHA_F * (d1[r] - m));
        #pragma unroll
        for (int off = 32; off > 0; off >>= 1)
            s += __shfl_xor(s, off, 64);
        if (lane == 0) ssum[wid][r] = s;
    }
    __syncthreads();
    if (tid < 16)
        rinv[tid] = 1.0f / ((ssum[0][tid] + ssum[1][tid]) +
                            (ssum[2][tid] + ssum[3][tid]));
    __syncthreads();

    // outputs (paired float2: clusters 2t, 2t+1)
    #pragma unroll
    for (int r = 0; r < 16; ++r) {
        const size_t row = (size_t)(r0 + r);
        const float m = rmin[r], inv = rinv[r];
        float w0 = d0[r] * (expf(-ALPHA_F * (d0[r] - m)) * inv);
        float w1 = d1[r] * (expf(-ALPHA_F * (d1[r] - m)) * inv);
        float2 dv = {d0[r], d1[r]};
        float2 wv = {w0, w1};
        ((float2*)(dist + row * NK))[tid] = dv;
        ((float2*)(wout + row * NK))[tid] = wv;
    }
}

// ---------------------------------------------------------------------------
extern "C" void kernel_launch(void* const* d_in, const int* in_sizes, int n_in,
                              void* d_out, int out_size, void* d_ws, size_t ws_size,
                              hipStream_t stream) {
    const float* x    = (const float*)d_in[0];
    const float* reps = (const float*)d_in[1];
    const float* W1   = (const float*)d_in[2];
    const float* b1   = (const float*)d_in[3];
    const float* W2   = (const float*)d_in[4];
    const float* b2   = (const float*)d_in[5];
    const float* W3   = (const float*)d_in[6];
    const float* b3   = (const float*)d_in[7];
    const float* W4   = (const float*)d_in[8];
    const float* b4   = (const float*)d_in[9];

    float* out   = (float*)d_out;
    float* wout  = out;                                          // [8192,512]
    float* dist  = out + (size_t)NB * NK;                        // [8192,512]
    float* recon = out + (size_t)2 * NB * NK;                    // [8192,784]
    float* emb   = out + (size_t)2 * NB * NK + (size_t)NB * ND;  // [8192,32]

    // Scratch aliased into output regions not yet written at time of use:
    //  recon region (24.5 MiB): x hi/lo fp16 planes (dead after GEMM1).
    //  dist region (16 MiB): h fp32 (8 MiB) + h2 hi/lo planes (4+4 MiB).
    //  wout region: W1T/W4T hi/lo planes (1.6 MiB); dead before dist_kernel.
    _Float16* xhi   = (_Float16*)recon;
    _Float16* xlo   = xhi + (size_t)NB * ND;
    float*    h     = dist;
    _Float16* h2hi  = (_Float16*)(dist + (size_t)NB * NH);
    _Float16* h2lo  = h2hi + (size_t)NB * NH;
    _Float16* w1thi = (_Float16*)wout;
    _Float16* w1tlo = w1thi + (size_t)NH * ND;
    _Float16* w4thi = w1tlo + (size_t)NH * ND;
    _Float16* w4tlo = w4thi + (size_t)ND * NH;

    // 0) splits
    split_x_kernel<<<(NB * ND / 4 + 255) / 256, 256, 0, stream>>>(
        x, xhi, xlo, NB * ND / 4);
    splitw_kernel<<<NH, 256, 0, stream>>>(W1, w1thi, w1tlo, ND, NH);  // -> [256][784]
    splitw_kernel<<<ND, 256, 0, stream>>>(W4, w4thi, w4tlo, NH, ND);  // -> [784][256]

    // 1) h = relu(x @ W1 + b1)   M=8192 N=256 K=784, 25 K-steps (tail zero-filled)
    mfma_gemm<4, true><<<dim3(128, 4), 256, 0, stream>>>(
        xhi, xlo, w1thi, w1tlo, b1, h, NH, ND, 25);
    // 2) emb + h2 (fp16 planes)
    mid_kernel<<<NB / 16, 256, 0, stream>>>(h, W2, b2, W3, b3, emb, h2hi, h2lo);
    // 3) recon = h2 @ W4 + b4    M=8192 N=784 K=256, 8 K-steps
    mfma_gemm<3, false><<<dim3(128, 13), 256, 0, stream>>>(
        h2hi, h2lo, w4thi, w4tlo, b4, recon, ND, NH, 8);
    // 4) distances + softmin
    dist_kernel<<<NB / 16, 256, 0, stream>>>(emb, reps, dist, wout);
}

// Round 5
// 190.752 us; speedup vs baseline: 1.1613x; 1.1613x over previous
//
#include <hip/hip_runtime.h>
#include <cstddef>

// Sizes (fixed per reference): B=8192, D=784, H=256, E=32, K=512
#define NB 8192
#define ND 784
#define NH 256
#define NE 32
#define NK 512
#define ALPHA_F 1000.0f

typedef _Float16 h8 __attribute__((ext_vector_type(8)));
typedef _Float16 h4 __attribute__((ext_vector_type(4)));
typedef float f32x4 __attribute__((ext_vector_type(4)));

// ---------------------------------------------------------------------------
// Split fp32 -> (hi fp16, lo fp16 scaled by 2^11).  w ~= hi + lo * 2^-11,
// representation error ~2^-23|w|.  fp16*fp16 products are exact in the fp32
// MFMA accumulator, so a 3/4-term product expansion is fp32-class accurate.
// ---------------------------------------------------------------------------
__global__ __launch_bounds__(256)
void split_x_kernel(const float* __restrict__ x, _Float16* __restrict__ xhi,
                    _Float16* __restrict__ xlo, int n4) {
    int i = blockIdx.x * 256 + threadIdx.x;
    if (i >= n4) return;
    float4 v = ((const float4*)x)[i];
    float vv[4] = {v.x, v.y, v.z, v.w};
    h4 hi, lo;
    #pragma unroll
    for (int j = 0; j < 4; ++j) {
        _Float16 hh = (_Float16)vv[j];
        float r = vv[j] - (float)hh;
        hi[j] = hh;
        lo[j] = (_Float16)(r * 2048.0f);
    }
    ((h4*)xhi)[i] = hi;
    ((h4*)xlo)[i] = lo;
}

// W [K][N] fp32  ->  WT_hi/lo [N][K] fp16 (transposed, split). One block per n.
__global__ __launch_bounds__(256)
void splitw_kernel(const float* __restrict__ W, _Float16* __restrict__ hi,
                   _Float16* __restrict__ lo, int K, int N) {
    const int n = blockIdx.x;
    for (int k = threadIdx.x; k < K; k += 256) {
        float w = W[(size_t)k * N + n];
        _Float16 hh = (_Float16)w;
        float r = w - (float)hh;
        hi[(size_t)n * K + k] = hh;
        lo[(size_t)n * K + k] = (_Float16)(r * 2048.0f);
    }
}

// ---------------------------------------------------------------------------
// MFMA split-fp16 GEMM: C[M,N] = op(A[M,K] @ W[K,N] + bias)
// A given as hi/lo fp16 planes [M][K]; W given TRANSPOSED as hi/lo [N][K].
// Tile 64x64, BK=32, 256 threads = 4 waves, wave = 32x32 via 2x2 MFMA tiles
// of v_mfma_f32_16x16x32_f16.  TERMS=4: full hh+mid+ll (fp32-class, encoder);
// TERMS=3: drop ll (decoder).  K ragged: trailing 8-elem chunks zero-filled.
// LDS rows padded to 40 fp16 (80 B) to spread bank groups.
// ---------------------------------------------------------------------------
template<int TERMS, bool RELU>
__global__ __launch_bounds__(256)
void mfma_gemm(const _Float16* __restrict__ Ahi, const _Float16* __restrict__ Alo,
               const _Float16* __restrict__ WThi, const _Float16* __restrict__ WTlo,
               const float* __restrict__ bias, float* __restrict__ C,
               int N, int K, int KS) {
    __shared__ _Float16 smem[4 * 64 * 40];
    const int PA_HI = 0, PA_LO = 2560, PB_HI = 5120, PB_LO = 7680;

    const int tid = threadIdx.x;
    const int bm  = blockIdx.x * 64;
    const int bn  = blockIdx.y * 64;

    // staging: thread -> (row, 8-elem k-chunk)
    const int srow = tid >> 2;
    const int sq   = (tid & 3) * 8;
    const int arow_g = bm + srow;
    int brow_g = bn + srow; if (brow_g > N - 1) brow_g = N - 1;  // G4 edge tile

    const _Float16* pAhi = Ahi + (size_t)arow_g * K;
    const _Float16* pAlo = Alo + (size_t)arow_g * K;
    const _Float16* pBhi = WThi + (size_t)brow_g * K;
    const _Float16* pBlo = WTlo + (size_t)brow_g * K;

    auto ld8 = [&](const _Float16* p, int k) -> h8 {
        if (k + 8 <= K) return *(const h8*)(p + k);
        h8 z = {};
        return z;
    };

    h8 ra_hi = ld8(pAhi, sq), ra_lo = ld8(pAlo, sq);
    h8 rb_hi = ld8(pBhi, sq), rb_lo = ld8(pBlo, sq);

    // fragment coords
    const int lane = tid & 63;
    const int wv   = tid >> 6;
    const int mb   = (wv >> 1) * 32;
    const int nb   = (wv & 1) * 32;
    const int li   = lane & 15;
    const int kq   = (lane >> 4) * 8;

    f32x4 acc0[2][2] = {};
    f32x4 acc1[2][2] = {};
    f32x4 acc2[2][2] = {};

    const int soff = srow * 40 + sq;

    for (int s = 0; s < KS; ++s) {
        *(h8*)&smem[PA_HI + soff] = ra_hi;
        *(h8*)&smem[PA_LO + soff] = ra_lo;
        *(h8*)&smem[PB_HI + soff] = rb_hi;
        *(h8*)&smem[PB_LO + soff] = rb_lo;
        __syncthreads();

        if (s + 1 < KS) {
            const int kn = (s + 1) * 32 + sq;
            ra_hi = ld8(pAhi, kn); ra_lo = ld8(pAlo, kn);
            rb_hi = ld8(pBhi, kn); rb_lo = ld8(pBlo, kn);
        }

        h8 ahi[2], alo[2], bhi[2], blo[2];
        #pragma unroll
        for (int t = 0; t < 2; ++t) {
            const int ao = (mb + t * 16 + li) * 40 + kq;
            ahi[t] = *(const h8*)&smem[PA_HI + ao];
            alo[t] = *(const h8*)&smem[PA_LO + ao];
            const int bo = (nb + t * 16 + li) * 40 + kq;
            bhi[t] = *(const h8*)&smem[PB_HI + bo];
            blo[t] = *(const h8*)&smem[PB_LO + bo];
        }
        #pragma unroll
        for (int tm = 0; tm < 2; ++tm)
            #pragma unroll
            for (int tn = 0; tn < 2; ++tn) {
                acc0[tm][tn] = __builtin_amdgcn_mfma_f32_16x16x32_f16(
                    ahi[tm], bhi[tn], acc0[tm][tn], 0, 0, 0);
                acc1[tm][tn] = __builtin_amdgcn_mfma_f32_16x16x32_f16(
                    ahi[tm], blo[tn], acc1[tm][tn], 0, 0, 0);
                acc1[tm][tn] = __builtin_amdgcn_mfma_f32_16x16x32_f16(
                    alo[tm], bhi[tn], acc1[tm][tn], 0, 0, 0);
                if (TERMS == 4)
                    acc2[tm][tn] = __builtin_amdgcn_mfma_f32_16x16x32_f16(
                        alo[tm], blo[tn], acc2[tm][tn], 0, 0, 0);
            }
        __syncthreads();
    }

    const float c1 = 1.0f / 2048.0f;
    const float c2 = c1 * c1;
    const int quad = lane >> 4;
    #pragma unroll
    for (int tm = 0; tm < 2; ++tm)
        #pragma unroll
        for (int tn = 0; tn < 2; ++tn) {
            const int n = bn + nb + tn * 16 + li;
            if (n < N) {
                const float bv = bias[n];
                #pragma unroll
                for (int r = 0; r < 4; ++r) {
                    const int m = bm + mb + tm * 16 + quad * 4 + r;
                    float v = acc0[tm][tn][r] + c1 * acc1[tm][tn][r];
                    if (TERMS == 4) v += c2 * acc2[tm][tn][r];
                    v += bv;
                    if (RELU) v = fmaxf(v, 0.f);
                    C[(size_t)m * N + n] = v;
                }
            }
        }
}

// ---------------------------------------------------------------------------
// Fused: emb[B,32] = h@W2+b2 (fp32, precision-critical);
//        h2 = relu(emb@W3+b3) emitted as fp16 hi/lo planes for the MFMA GEMM.
// Block = 16 rows, 256 threads, 512 blocks.
// ---------------------------------------------------------------------------
__global__ __launch_bounds__(256)
void mid_kernel(const float* __restrict__ h, const float* __restrict__ W2,
                const float* __restrict__ b2, const float* __restrict__ W3,
                const float* __restrict__ b3, float* __restrict__ emb,
                _Float16* __restrict__ h2hi, _Float16* __restrict__ h2lo) {
    __shared__ float es[16][32];
    const int tid = threadIdx.x;
    const int r0  = blockIdx.x * 16;

    #pragma unroll
    for (int half = 0; half < 2; ++half) {
        const int o   = tid + half * 256;
        const int row = o >> 5;
        const int col = o & 31;
        const float* hrow = h + (size_t)(r0 + row) * NH;
        float acc0 = 0.f, acc1 = 0.f;
        #pragma unroll 4
        for (int k = 0; k < NH; k += 4) {
            float4 hv = *(const float4*)(hrow + k);
            acc0 = fmaf(hv.x, W2[(k + 0) * NE + col], acc0);
            acc1 = fmaf(hv.y, W2[(k + 1) * NE + col], acc1);
            acc0 = fmaf(hv.z, W2[(k + 2) * NE + col], acc0);
            acc1 = fmaf(hv.w, W2[(k + 3) * NE + col], acc1);
        }
        float v = acc0 + acc1 + b2[col];
        es[row][col] = v;
        emb[(size_t)r0 * NE + o] = v;
    }
    __syncthreads();

    const int col = tid;
    float acc[16];
    #pragma unroll
    for (int r = 0; r < 16; ++r) acc[r] = 0.f;
    #pragma unroll
    for (int k = 0; k < NE; ++k) {
        float w = W3[k * NH + col];
        #pragma unroll
        for (int r = 0; r < 16; ++r) acc[r] = fmaf(es[r][k], w, acc[r]);
    }
    const float bb = b3[col];
    #pragma unroll
    for (int r = 0; r < 16; ++r) {
        float v = acc[r] + bb;
        v = v > 0.f ? v : 0.f;
        _Float16 hh = (_Float16)v;
        float rr = v - (float)hh;
        h2hi[(size_t)(r0 + r) * NH + col] = hh;
        h2lo[(size_t)(r0 + r) * NH + col] = (_Float16)(rr * 2048.0f);
    }
}

// ---------------------------------------------------------------------------
// Distances + stable softmin, v3.
// 1024 blocks x 512 threads (8 waves). Thread owns ONE cluster (tid) for
// 8 rows: reps = 32 VGPRs, d[8]+e[8] = 16 -> ~70 VGPR, no spill
// (__launch_bounds__(512,4) caps at 128). Row reductions via padded LDS
// transpose ([8][520], conflict-free both ways): wave w reduces row w with
// 2x ds_read_b128 + one 6-step shuffle — instead of 96 serial swizzles.
// ---------------------------------------------------------------------------
__global__ __launch_bounds__(512, 4)
void dist_kernel(const float* __restrict__ emb, const float* __restrict__ reps,
                 float* __restrict__ dist, float* __restrict__ wout) {
    __shared__ float es[8][32];       // emb tile
    __shared__ float tr[8][520];      // transpose buffer [row][cluster], padded
    __shared__ float rmin[8];
    __shared__ float rinv[8];

    const int tid = threadIdx.x;      // == cluster id
    const int r0  = blockIdx.x * 8;

    // stage emb tile (8 rows x 32)
    if (tid < 256) es[tid >> 5][tid & 31] = emb[(size_t)r0 * NE + tid];

    // reps for cluster tid -> 32 VGPRs (lane stride 128 B; L1/L2-resident)
    const float* rp = reps + (size_t)tid * NE;
    f32x4 rv[8];
    #pragma unroll
    for (int e4 = 0; e4 < 8; ++e4) rv[e4] = ((const f32x4*)rp)[e4];
    __syncthreads();

    // distances: d[r] = sum_j (es[r][j] - rv[j])^2   (LDS reads broadcast)
    float d[8];
    #pragma unroll
    for (int r = 0; r < 8; ++r) {
        float a = 0.f;
        #pragma unroll
        for (int e4 = 0; e4 < 8; ++e4) {
            f32x4 ev = *(const f32x4*)&es[r][e4 * 4];
            #pragma unroll
            for (int j = 0; j < 4; ++j) {
                float t = ev[j] - rv[e4][j];
                a = fmaf(t, t, a);
            }
        }
        d[r] = a;
    }

    const int lane = tid & 63;
    const int wv   = tid >> 6;        // wave id 0..7 == row it reduces

    // ---- min reduction via transpose ----
    #pragma unroll
    for (int r = 0; r < 8; ++r) tr[r][tid] = d[r];
    __syncthreads();
    {
        f32x4 a = *(const f32x4*)&tr[wv][lane * 8];
        f32x4 b = *(const f32x4*)&tr[wv][lane * 8 + 4];
        float m = fminf(fminf(fminf(a[0], a[1]), fminf(a[2], a[3])),
                        fminf(fminf(b[0], b[1]), fminf(b[2], b[3])));
        #pragma unroll
        for (int off = 32; off > 0; off >>= 1)
            m = fminf(m, __shfl_xor(m, off, 64));
        if (lane == 0) rmin[wv] = m;
    }
    __syncthreads();

    // ---- exponentials + sum reduction via transpose ----
    float e[8];
    #pragma unroll
    for (int r = 0; r < 8; ++r) {
        e[r] = expf(-ALPHA_F * (d[r] - rmin[r]));
        tr[r][tid] = e[r];
    }
    __syncthreads();
    {
        f32x4 a = *(const f32x4*)&tr[wv][lane * 8];
        f32x4 b = *(const f32x4*)&tr[wv][lane * 8 + 4];
        float s = ((a[0] + a[1]) + (a[2] + a[3])) +
                  ((b[0] + b[1]) + (b[2] + b[3]));
        #pragma unroll
        for (int off = 32; off > 0; off >>= 1)
            s += __shfl_xor(s, off, 64);
        if (lane == 0) rinv[wv] = 1.0f / s;
    }
    __syncthreads();

    // ---- outputs (lane-contiguous dword runs) ----
    #pragma unroll
    for (int r = 0; r < 8; ++r) {
        const size_t row = (size_t)(r0 + r);
        dist[row * NK + tid] = d[r];
        wout[row * NK + tid] = d[r] * (e[r] * rinv[r]);
    }
}

// ---------------------------------------------------------------------------
extern "C" void kernel_launch(void* const* d_in, const int* in_sizes, int n_in,
                              void* d_out, int out_size, void* d_ws, size_t ws_size,
                              hipStream_t stream) {
    const float* x    = (const float*)d_in[0];
    const float* reps = (const float*)d_in[1];
    const float* W1   = (const float*)d_in[2];
    const float* b1   = (const float*)d_in[3];
    const float* W2   = (const float*)d_in[4];
    const float* b2   = (const float*)d_in[5];
    const float* W3   = (const float*)d_in[6];
    const float* b3   = (const float*)d_in[7];
    const float* W4   = (const float*)d_in[8];
    const float* b4   = (const float*)d_in[9];

    float* out   = (float*)d_out;
    float* wout  = out;                                          // [8192,512]
    float* dist  = out + (size_t)NB * NK;                        // [8192,512]
    float* recon = out + (size_t)2 * NB * NK;                    // [8192,784]
    float* emb   = out + (size_t)2 * NB * NK + (size_t)NB * ND;  // [8192,32]

    // Scratch aliased into output regions not yet written at time of use:
    //  recon region (24.5 MiB): x hi/lo fp16 planes (dead after GEMM1).
    //  dist region (16 MiB): h fp32 (8 MiB) + h2 hi/lo planes (4+4 MiB).
    //  wout region: W1T/W4T hi/lo planes (1.6 MiB); dead before dist_kernel.
    _Float16* xhi   = (_Float16*)recon;
    _Float16* xlo   = xhi + (size_t)NB * ND;
    float*    h     = dist;
    _Float16* h2hi  = (_Float16*)(dist + (size_t)NB * NH);
    _Float16* h2lo  = h2hi + (size_t)NB * NH;
    _Float16* w1thi = (_Float16*)wout;
    _Float16* w1tlo = w1thi + (size_t)NH * ND;
    _Float16* w4thi = w1tlo + (size_t)NH * ND;
    _Float16* w4tlo = w4thi + (size_t)ND * NH;

    // 0) splits
    split_x_kernel<<<(NB * ND / 4 + 255) / 256, 256, 0, stream>>>(
        x, xhi, xlo, NB * ND / 4);
    splitw_kernel<<<NH, 256, 0, stream>>>(W1, w1thi, w1tlo, ND, NH);  // -> [256][784]
    splitw_kernel<<<ND, 256, 0, stream>>>(W4, w4thi, w4tlo, NH, ND);  // -> [784][256]

    // 1) h = relu(x @ W1 + b1)   M=8192 N=256 K=784, 25 K-steps (tail zero-filled)
    mfma_gemm<4, true><<<dim3(128, 4), 256, 0, stream>>>(
        xhi, xlo, w1thi, w1tlo, b1, h, NH, ND, 25);
    // 2) emb + h2 (fp16 planes)
    mid_kernel<<<NB / 16, 256, 0, stream>>>(h, W2, b2, W3, b3, emb, h2hi, h2lo);
    // 3) recon = h2 @ W4 + b4    M=8192 N=784 K=256, 8 K-steps
    mfma_gemm<3, false><<<dim3(128, 13), 256, 0, stream>>>(
        h2hi, h2lo, w4thi, w4tlo, b4, recon, ND, NH, 8);
    // 4) distances + softmin
    dist_kernel<<<NB / 8, 512, 0, stream>>>(emb, reps, dist, wout);
}